// Round 6
// baseline (351.806 us; speedup 1.0000x reference)
//
#include <hip/hip_runtime.h>
#include <hip/hip_bf16.h>

using bf16x8 = __attribute__((ext_vector_type(8))) __bf16;
using f32x4  = __attribute__((ext_vector_type(4))) float;

#define NB 8
#define SEQ 1024
#define HEADS 16
#define HD 64
#define EMB 1024

// exp domain: native exp2, fold log2(e) into the Q prescale.
#if __has_builtin(__builtin_amdgcn_exp2f)
  #define EXPD(x) __builtin_amdgcn_exp2f(x)
  #define QSCALE  0.04508422f    /* (1/32) * log2(e) */
  #define MASKV  -4.5084e18f     /* -1e20 * QSCALE   */
#else
  #define EXPD(x) __expf(x)
  #define QSCALE  0.03125f
  #define MASKV  -3.125e18f
#endif

// ---------------- Kernel 0: prep = mask bit-pack + Wo f32->bf16 (fused launches) ----------------
__global__ __launch_bounds__(256) void prep_kernel(const int* __restrict__ mask,
                                                   unsigned long long* __restrict__ mp,
                                                   const float* __restrict__ Wo,
                                                   __bf16* __restrict__ Wob)
{
    const int bid = blockIdx.x, t = threadIdx.x;
    if (bid < NB * SEQ) {
        const int n = bid & 7, row = bid >> 3;
        const int w = t >> 6, lane = t & 63;
        const int* m = mask + ((size_t)n * SEQ + row) * SEQ;
        #pragma unroll
        for (int i = 0; i < 4; ++i) {
            unsigned long long b = __ballot(m[i * 256 + w * 64 + lane] != 0);
            if (lane == 0) mp[((size_t)n * SEQ + row) * 16 + i * 4 + w] = b;
        }
    } else {
        const size_t i = (size_t)(bid - NB * SEQ) * 256 + t;
        float4 f = *(const float4*)&Wo[i * 4];
        union { __bf16 b[4]; uint2 u; } tmp;
        tmp.b[0] = (__bf16)f.x; tmp.b[1] = (__bf16)f.y;
        tmp.b[2] = (__bf16)f.z; tmp.b[3] = (__bf16)f.w;
        *(uint2*)&Wob[i * 4] = tmp.u;
    }
}

// ---------------- Kernel 1: per-head projection, MFMA (unchanged from R5) ----------------
__global__ __launch_bounds__(256, 4) void proj_mfma(
    const float* __restrict__ q_in, const float* __restrict__ k_in, const float* __restrict__ v_in,
    const float* __restrict__ Wq, const float* __restrict__ Wk, const float* __restrict__ Wv,
    __bf16* __restrict__ qp, __bf16* __restrict__ kp, __bf16* __restrict__ vpt)
{
    const int z = blockIdx.z;
    const float* X  = (z == 0) ? q_in : (z == 1) ? k_in : v_in;
    const float* Wf = (z == 0) ? Wq   : (z == 1) ? Wk   : Wv;

    __shared__ __align__(16) __bf16 Wb[64 * 72];
    __shared__ __align__(16) __bf16 Xb[64 * 72];
    const int t = threadIdx.x;
    const int nh = blockIdx.y, n = nh >> 4, h = nh & 15;
    const int l0 = blockIdx.x * 64;
    for (int i = t; i < 4096; i += 256)
        Wb[(i >> 6) * 72 + (i & 63)] = (__bf16)Wf[i];
    {
        const int row = t >> 2, seg = (t & 3) * 16;
        const float* src = X + ((size_t)(n * SEQ + l0 + row)) * EMB + h * 64 + seg;
        union { __bf16 b[16]; uint4 u[2]; } tmp;
        #pragma unroll
        for (int jj = 0; jj < 4; ++jj) {
            float4 f = ((const float4*)src)[jj];
            tmp.b[jj*4+0] = (__bf16)f.x; tmp.b[jj*4+1] = (__bf16)f.y;
            tmp.b[jj*4+2] = (__bf16)f.z; tmp.b[jj*4+3] = (__bf16)f.w;
        }
        *(uint4*)&Xb[row * 72 + seg]     = tmp.u[0];
        *(uint4*)&Xb[row * 72 + seg + 8] = tmp.u[1];
    }
    __syncthreads();
    const int w = t >> 6, lane = t & 63, quad = lane >> 4, lr = lane & 15;
    bf16x8 af[2];
    #pragma unroll
    for (int ks = 0; ks < 2; ++ks)
        af[ks] = *(const bf16x8*)&Xb[(w * 16 + lr) * 72 + ks * 32 + quad * 8];
    const f32x4 zero4 = {0.f, 0.f, 0.f, 0.f};
    f32x4 acc[4];
    #pragma unroll
    for (int et = 0; et < 4; ++et) {
        acc[et] = zero4;
        #pragma unroll
        for (int ks = 0; ks < 2; ++ks) {
            bf16x8 bfrag = *(const bf16x8*)&Wb[(et * 16 + lr) * 72 + ks * 32 + quad * 8];
            acc[et] = __builtin_amdgcn_mfma_f32_16x16x32_bf16(af[ks], bfrag, acc[et], 0, 0, 0);
        }
    }
    if (z == 0) {
        #pragma unroll
        for (int et = 0; et < 4; ++et) acc[et] *= QSCALE;
    }
    __syncthreads();
    if (z < 2) {
        #pragma unroll
        for (int et = 0; et < 4; ++et)
            #pragma unroll
            for (int rr = 0; rr < 4; ++rr)
                Xb[(w * 16 + quad * 4 + rr) * 72 + et * 16 + lr] = (__bf16)acc[et][rr];
        __syncthreads();
        const int row = t >> 2, seg = (t & 3) * 16;
        uint4 a = *(uint4*)&Xb[row * 72 + seg];
        uint4 b = *(uint4*)&Xb[row * 72 + seg + 8];
        __bf16* outp = (z == 0) ? qp : kp;
        __bf16* dst = outp + (size_t)nh * 65536 + (size_t)(l0 + row) * 64 + seg;
        *(uint4*)&dst[0] = a;
        *(uint4*)&dst[8] = b;
    } else {
        #pragma unroll
        for (int et = 0; et < 4; ++et)
            #pragma unroll
            for (int rr = 0; rr < 4; ++rr)
                Xb[(et * 16 + lr) * 72 + w * 16 + quad * 4 + rr] = (__bf16)acc[et][rr];
        __syncthreads();
        const int e = t >> 2, seg = (t & 3) * 16;
        uint4 a = *(uint4*)&Xb[e * 72 + seg];
        uint4 b = *(uint4*)&Xb[e * 72 + seg + 8];
        __bf16* dst = vpt + (size_t)nh * 65536 + (size_t)e * SEQ + l0 + seg;
        *(uint4*)&dst[0] = a;
        *(uint4*)&dst[8] = b;
    }
}

// ---------------- Kernel 2: MFMA flash attention, barrier-free ----------------
// K/V fragments loaded global->registers (L1/L2-resident, XCD-pinned); LDS only for
// the per-wave P round-trip (in-order DS + lgkmcnt, no __syncthreads in the loop).
__global__ __launch_bounds__(256, 4) void attn_mfma(
    const __bf16* __restrict__ qp, const __bf16* __restrict__ kp, const __bf16* __restrict__ vpt,
    const unsigned long long* __restrict__ mp, __bf16* __restrict__ attn_out)
{
    __shared__ __align__(16) __bf16 Ps[4][2][16 * 72];  // per-wave, per-group [q][key]
    const int t = threadIdx.x, w = t >> 6, lane = t & 63, quad = lane >> 4, lr = lane & 15;
    const int bid = blockIdx.x;
    const int nh = bid & 127, qg = bid >> 7;       // same head -> same XCD (stride-128 blocks)
    const int n = nh >> 4, h = nh & 15;
    const int q0 = qg * 128;
    const __bf16* Q  = qp  + (size_t)nh * 65536;
    const __bf16* K  = kp  + (size_t)nh * 65536;
    const __bf16* VT = vpt + (size_t)nh * 65536;

    int qrow[2];
    bf16x8 qf[2][2];
    const unsigned long long* mrow[2];
    #pragma unroll
    for (int g = 0; g < 2; ++g) {
        qrow[g] = q0 + g * 64 + w * 16 + lr;
        qf[g][0] = *(const bf16x8*)&Q[(size_t)qrow[g] * 64 + quad * 8];
        qf[g][1] = *(const bf16x8*)&Q[(size_t)qrow[g] * 64 + 32 + quad * 8];
        mrow[g] = mp + ((size_t)n * SEQ + qrow[g]) * 16;
    }

    const f32x4 zero4 = {0.f, 0.f, 0.f, 0.f};
    f32x4 O[2][4];
    #pragma unroll
    for (int g = 0; g < 2; ++g)
        #pragma unroll
        for (int mt = 0; mt < 4; ++mt) O[g][mt] = zero4;
    float l_part[2] = {0.f, 0.f};

    for (int kc = 0; kc < 16; ++kc) {
        // ---- S^T = K @ Q^T, one q-group at a time (K-frags from global; L1 hit on g=1)
        #pragma unroll
        for (int g = 0; g < 2; ++g) {
            f32x4 S[4];
            #pragma unroll
            for (int kt = 0; kt < 4; ++kt) {
                const __bf16* kb = &K[(size_t)(kc * 64 + kt * 16 + lr) * 64 + quad * 8];
                bf16x8 kf0 = *(const bf16x8*)&kb[0];
                bf16x8 kf1 = *(const bf16x8*)&kb[32];
                S[kt] = __builtin_amdgcn_mfma_f32_16x16x32_bf16(kf0, qf[g][0], zero4, 0, 0, 0);
                S[kt] = __builtin_amdgcn_mfma_f32_16x16x32_bf16(kf1, qf[g][1], S[kt], 0, 0, 0);
            }
            const unsigned long long mword = mrow[g][kc];
            const unsigned int mlo = (unsigned int)(mword >> (quad * 4));
            const unsigned int mhi = (unsigned int)(mword >> (32 + quad * 4));
            float lsum = 0.f;
            #pragma unroll
            for (int kt = 0; kt < 4; ++kt) {
                union { __bf16 b[4]; uint2 u; } pk;
                #pragma unroll
                for (int r = 0; r < 4; ++r) {
                    unsigned int bits = (kt < 2) ? mlo : mhi;
                    int sh = (kt & 1) * 16 + r;
                    float sv = ((bits >> sh) & 1u) ? S[kt][r] : MASKV;
                    float ev = EXPD(sv);            // masked -> exp underflows to exactly 0
                    lsum += ev;
                    pk.b[r] = (__bf16)ev;
                }
                *(uint2*)&Ps[w][g][lr * 72 + kt * 16 + quad * 4] = pk.u;
            }
            l_part[g] += lsum;
        }
        __asm__ __volatile__("s_waitcnt lgkmcnt(0)" ::: "memory");  // wave-local P visibility
        // ---- O^T += V^T @ P^T (V-frags from global VT, shared across both groups)
        #pragma unroll
        for (int ks = 0; ks < 2; ++ks) {
            bf16x8 pf0 = *(const bf16x8*)&Ps[w][0][lr * 72 + ks * 32 + quad * 8];
            bf16x8 pf1 = *(const bf16x8*)&Ps[w][1][lr * 72 + ks * 32 + quad * 8];
            #pragma unroll
            for (int mt = 0; mt < 4; ++mt) {
                bf16x8 vf = *(const bf16x8*)&VT[(size_t)(mt * 16 + lr) * SEQ + kc * 64 + ks * 32 + quad * 8];
                O[0][mt] = __builtin_amdgcn_mfma_f32_16x16x32_bf16(vf, pf0, O[0][mt], 0, 0, 0);
                O[1][mt] = __builtin_amdgcn_mfma_f32_16x16x32_bf16(vf, pf1, O[1][mt], 0, 0, 0);
            }
        }
    }
    #pragma unroll
    for (int g = 0; g < 2; ++g) {
        float l = l_part[g];
        l += __shfl_xor(l, 16, 64);
        l += __shfl_xor(l, 32, 64);
        const float linv = 1.0f / l;
        #pragma unroll
        for (int mt = 0; mt < 4; ++mt) {
            union { __bf16 b[4]; uint2 u; } pk;
            #pragma unroll
            for (int r = 0; r < 4; ++r) pk.b[r] = (__bf16)(O[g][mt][r] * linv);
            *(uint2*)&attn_out[((size_t)n * SEQ + qrow[g]) * EMB + h * 64 + mt * 16 + quad * 4] = pk.u;
        }
    }
}

// ---------------- Kernel 3: out = A(8192x1024) @ Wob^T + bo; 128x128 tile, 64x64 wave-tile ----------------
// Unpadded stride-32 LDS tiles: b128 read/write bank loads are perfectly balanced at 64-B row stride.
__global__ __launch_bounds__(256, 2) void out_gemm_mfma(
    const __bf16* __restrict__ A, const __bf16* __restrict__ B,
    const float* __restrict__ bo, float* __restrict__ out)
{
    __shared__ __align__(16) __bf16 As[128 * 32];
    __shared__ __align__(16) __bf16 Bs[128 * 32];
    const int t = threadIdx.x, w = t >> 6, lane = t & 63, quad = lane >> 4, lr = lane & 15;
    const int wr = (w >> 1) * 64, wc = (w & 1) * 64;
    const int r0 = blockIdx.y * 128, e0 = blockIdx.x * 128;
    const f32x4 zero4 = {0.f, 0.f, 0.f, 0.f};
    f32x4 acc[4][4];
    #pragma unroll
    for (int mt = 0; mt < 4; ++mt)
        #pragma unroll
        for (int nt = 0; nt < 4; ++nt) acc[mt][nt] = zero4;
    for (int k0 = 0; k0 < 1024; k0 += 32) {
        __syncthreads();
        #pragma unroll
        for (int c = t; c < 512; c += 256) {
            int row = c >> 2, seg = c & 3;
            *(uint4*)&As[row * 32 + seg * 8] =
                *(const uint4*)&A[(size_t)(r0 + row) * EMB + k0 + seg * 8];
            *(uint4*)&Bs[row * 32 + seg * 8] =
                *(const uint4*)&B[(size_t)(e0 + row) * EMB + k0 + seg * 8];
        }
        __syncthreads();
        bf16x8 af[4], bf[4];
        #pragma unroll
        for (int mt = 0; mt < 4; ++mt)
            af[mt] = *(const bf16x8*)&As[(wr + mt * 16 + lr) * 32 + quad * 8];
        #pragma unroll
        for (int nt = 0; nt < 4; ++nt)
            bf[nt] = *(const bf16x8*)&Bs[(wc + nt * 16 + lr) * 32 + quad * 8];
        #pragma unroll
        for (int mt = 0; mt < 4; ++mt)
            #pragma unroll
            for (int nt = 0; nt < 4; ++nt)
                acc[mt][nt] = __builtin_amdgcn_mfma_f32_16x16x32_bf16(af[mt], bf[nt], acc[mt][nt], 0, 0, 0);
    }
    float bv[4];
    #pragma unroll
    for (int nt = 0; nt < 4; ++nt) bv[nt] = bo[e0 + wc + nt * 16 + lr];
    #pragma unroll
    for (int mt = 0; mt < 4; ++mt)
        #pragma unroll
        for (int nt = 0; nt < 4; ++nt)
            #pragma unroll
            for (int rr = 0; rr < 4; ++rr)
                out[(size_t)(r0 + wr + mt * 16 + quad * 4 + rr) * EMB + e0 + wc + nt * 16 + lr] =
                    acc[mt][nt][rr] + bv[nt];
}

extern "C" void kernel_launch(void* const* d_in, const int* in_sizes, int n_in,
                              void* d_out, int out_size, void* d_ws, size_t ws_size,
                              hipStream_t stream) {
    const float* values = (const float*)d_in[0];
    const float* keys   = (const float*)d_in[1];
    const float* query  = (const float*)d_in[2];
    const int*   mask   = (const int*)d_in[3];
    const float* Wv     = (const float*)d_in[4];
    const float* Wk     = (const float*)d_in[5];
    const float* Wq     = (const float*)d_in[6];
    const float* Wo     = (const float*)d_in[7];
    const float* bo     = (const float*)d_in[8];
    float* out = (float*)d_out;

    const size_t per = (size_t)NB * HEADS * SEQ * HD;  // 8,388,608 elems
    __bf16* qp   = (__bf16*)d_ws;
    __bf16* kp   = qp + per;
    __bf16* vpt  = kp + per;                         // V transposed (N,H,64,SEQ)
    __bf16* attn = vpt + per;                        // (N*SEQ, EMB)
    __bf16* Wob  = attn + (size_t)NB * SEQ * EMB;
    unsigned long long* maskp = (unsigned long long*)(Wob + (size_t)EMB * EMB);

    prep_kernel<<<NB * SEQ + 1024, 256, 0, stream>>>(mask, maskp, Wo, Wob);
    proj_mfma<<<dim3(16, 128, 3), 256, 0, stream>>>(query, keys, values, Wq, Wk, Wv, qp, kp, vpt);
    attn_mfma<<<1024, 256, 0, stream>>>(qp, kp, vpt, maskp, attn);
    out_gemm_mfma<<<dim3(EMB / 128, NB * SEQ / 128), 256, 0, stream>>>(attn, Wob, bo, out);
}